// Round 7
// baseline (148.904 us; speedup 1.0000x reference)
//
#include <hip/hip_runtime.h>
#include <stdint.h>
#include <float.h>

using u64 = unsigned long long;
typedef float v2f __attribute__((ext_vector_type(2)));

constexpr int B_ = 2;
constexpr int NC = 512;
constexpr int NF = 8192;
constexpr int MT = 8192;

constexpr int TPB = 256;
constexpr int CF  = 16;            // j-chunks (512 j = 256 j-pairs each)
constexpr int TAIL_BLOCKS = 196;   // 64 + 64 + 4 + 64

#define DEVINL __device__ __forceinline__

// Packed fp32 ops (CDNA packed-math). Each is two correctly-rounded scalar
// fp32 ops — bit-identical to v_mul_f32/v_add_f32 per half. "s" operands are
// SGPR pairs fed straight from uniform s_loads of the pair-interleaved Q.
DEVINL v2f pk_mul_vs(v2f a, v2f b){ v2f d; asm("v_pk_mul_f32 %0, %1, %2" : "=v"(d) : "v"(a), "s"(b)); return d; }
DEVINL v2f pk_add_vv(v2f a, v2f b){ v2f d; asm("v_pk_add_f32 %0, %1, %2" : "=v"(d) : "v"(a), "v"(b)); return d; }
DEVINL v2f pk_add_vs(v2f a, v2f b){ v2f d; asm("v_pk_add_f32 %0, %1, %2" : "=v"(d) : "v"(a), "s"(b)); return d; }

// ---------------------------------------------------------------------------
// prep: pair-interleaved Q layout {x_2p, x_2p+1, y_2p, y_2p+1, z_2p, z_2p+1,
// w_2p, w_2p+1} (w = (x*x+y*y)+z*z, contract off — bit-exact numpy), so
// pairmin's block-uniform 32B reads land in SGPR pairs. Also zeroes counter.
// ---------------------------------------------------------------------------
__global__ __launch_bounds__(TPB) void prep(
    const float* __restrict__ coarse, const float* __restrict__ fine,
    const float* __restrict__ tgt,
    float* __restrict__ finep, float* __restrict__ tgtp,
    float* __restrict__ coarsep, unsigned* __restrict__ counter)
{
#pragma clang fp contract(off)
    int g = blockIdx.x * TPB + threadIdx.x;      // pair index
    if (g == 0) *counter = 0;
    if (g < B_ * NF / 2) {
        {
            const float* p = fine + (size_t)g * 6;
            float x0=p[0],y0=p[1],z0=p[2],x1=p[3],y1=p[4],z1=p[5];
            float* o = finep + (size_t)g * 8;
            o[0]=x0; o[1]=x1; o[2]=y0; o[3]=y1; o[4]=z0; o[5]=z1;
            o[6]=(x0*x0+y0*y0)+z0*z0;  o[7]=(x1*x1+y1*y1)+z1*z1;
        }
        {
            const float* p = tgt + (size_t)g * 6;
            float x0=p[0],y0=p[1],z0=p[2],x1=p[3],y1=p[4],z1=p[5];
            float* o = tgtp + (size_t)g * 8;
            o[0]=x0; o[1]=x1; o[2]=y0; o[3]=y1; o[4]=z0; o[5]=z1;
            o[6]=(x0*x0+y0*y0)+z0*z0;  o[7]=(x1*x1+y1*y1)+z1*z1;
        }
        if (g < B_ * NC / 2) {
            const float* p = coarse + (size_t)g * 6;
            float x0=p[0],y0=p[1],z0=p[2],x1=p[3],y1=p[4],z1=p[5];
            float* o = coarsep + (size_t)g * 8;
            o[0]=x0; o[1]=x1; o[2]=y0; o[3]=y1; o[4]=z0; o[5]=z1;
            o[6]=(x0*x0+y0*y0)+z0*z0;  o[7]=(x1*x1+y1*y1)+z1*z1;
        }
    }
}

// ---------------------------------------------------------------------------
// pairmin: 512 rows (2/thread) vs jplen j-PAIRS. Bit-exact numpy per pair:
//   d = (xx (+) qq) (+) (((-2x0)q0 (+) (-2x1)q1) (+) (-2x2)q2)
// (pre-negated prescale commutes with RN — verified absmax 0.0 R1-R6).
// One 32B uniform s_load per iteration feeds 4 pairs (2 rows x 2 j);
// depth-2 software pipeline covers SMEM latency.
// ---------------------------------------------------------------------------
template<bool ARGMIN>
DEVINL void pairmin_body(const float* __restrict__ P, const v2f* __restrict__ Qp,
                         int nP, int nQpairsB, int b, int row_base,
                         int jp0, int jplen, int chunk, int nRowsTot,
                         u64* __restrict__ outPack, unsigned* __restrict__ outVal)
{
#pragma clang fp contract(off)
    const int tid  = threadIdx.x;
    const int row0 = row_base + tid;
    const int row1 = row_base + tid + TPB;
    const float* p0 = P + ((size_t)b * nP + row0) * 3;
    const float* p1 = P + ((size_t)b * nP + row1) * 3;
    float a0 = p0[0], a1 = p0[1], a2 = p0[2];
    float e0 = p1[0], e1 = p1[1], e2 = p1[2];
    v2f r0x = {-2.0f*a0, -2.0f*a0}, r0y = {-2.0f*a1, -2.0f*a1}, r0z = {-2.0f*a2, -2.0f*a2};
    v2f r1x = {-2.0f*e0, -2.0f*e0}, r1y = {-2.0f*e1, -2.0f*e1}, r1z = {-2.0f*e2, -2.0f*e2};
    float xx0 = (a0*a0 + a1*a1) + a2*a2;
    float xx1 = (e0*e0 + e1*e1) + e2*e2;
    v2f v0xx = {xx0, xx0}, v1xx = {xx1, xx1};
    float db0 = FLT_MAX, db1 = FLT_MAX;   // row0: even/odd j chains
    float dc0 = FLT_MAX, dc1 = FLT_MAX;   // row1
    int jb0 = 0, jb1 = 0, jc0 = 0, jc1 = 0;

    const v2f* Q = Qp + ((size_t)b * nQpairsB + jp0) * 4;
    // depth-2 prefetch (block-uniform addresses -> scalar loads)
    v2f q0x = Q[0], q0y = Q[1], q0z = Q[2], q0w = Q[3];
    v2f q1x = Q[4], q1y = Q[5], q1z = Q[6], q1w = Q[7];
    int j = jp0 * 2;
    for (int k = 0; k < jplen; ++k) {
        const v2f* Qn = Q + (size_t)(k + 2) * 4;      // prefetch 2 ahead
        v2f nx = Qn[0], ny = Qn[1], nz = Qn[2], nw = Qn[3];  // (+64B overrun: padded)
        // row0
        v2f m0  = pk_mul_vs(r0x, q0x);
        v2f m1  = pk_mul_vs(r0y, q0y);
        v2f m2  = pk_mul_vs(r0z, q0z);
        v2f s01 = pk_add_vv(m0, m1);
        v2f sxy = pk_add_vv(s01, m2);      // == -(2*xy) bitwise
        v2f tt  = pk_add_vs(v0xx, q0w);
        v2f d0  = pk_add_vv(tt, sxy);      // == (xx+qq) - 2*xy bitwise
        // row1
        v2f n0  = pk_mul_vs(r1x, q0x);
        v2f n1  = pk_mul_vs(r1y, q0y);
        v2f n2  = pk_mul_vs(r1z, q0z);
        v2f t01 = pk_add_vv(n0, n1);
        v2f txy = pk_add_vv(t01, n2);
        v2f uu  = pk_add_vs(v1xx, q0w);
        v2f d1  = pk_add_vv(uu, txy);
        if (ARGMIN) {
            float c0 = fmaxf(d0.x, 0.0f), c1 = fmaxf(d0.y, 0.0f);
            bool t0 = c0 < db0;  db0 = t0 ? c0 : db0;  jb0 = t0 ? j     : jb0;
            bool t1 = c1 < db1;  db1 = t1 ? c1 : db1;  jb1 = t1 ? (j+1) : jb1;
            float g0 = fmaxf(d1.x, 0.0f), g1 = fmaxf(d1.y, 0.0f);
            bool u0 = g0 < dc0;  dc0 = u0 ? g0 : dc0;  jc0 = u0 ? j     : jc0;
            bool u1 = g1 < dc1;  dc1 = u1 ? g1 : dc1;  jc1 = u1 ? (j+1) : jc1;
        } else {
            // med3(d,0,best) == min(best, max(d,0)) for best>=0 — 1 op each
            db0 = __builtin_amdgcn_fmed3f(d0.x, 0.0f, db0);
            db1 = __builtin_amdgcn_fmed3f(d0.y, 0.0f, db1);
            dc0 = __builtin_amdgcn_fmed3f(d1.x, 0.0f, dc0);
            dc1 = __builtin_amdgcn_fmed3f(d1.y, 0.0f, dc1);
        }
        q0x = q1x; q0y = q1y; q0z = q1z; q0w = q1w;   // rotate pipeline (s_mov)
        q1x = nx;  q1y = ny;  q1z = nz;  q1w = nw;
        j += 2;
    }
    const size_t o0 = (size_t)chunk * nRowsTot + (size_t)b * nP;
    if (ARGMIN) {
        // even/odd chains track first occurrence per parity; on a value tie
        // the smaller index is the global first occurrence (np.argmin).
        bool o1 = (db1 < db0) || (db1 == db0 && jb1 < jb0);
        float dA = o1 ? db1 : db0;  int jA = o1 ? jb1 : jb0;
        bool o2 = (dc1 < dc0) || (dc1 == dc0 && jc1 < jc0);
        float dB = o2 ? dc1 : dc0;  int jB = o2 ? jc1 : jc0;
        outPack[o0 + row0] = ((u64)__float_as_uint(dA) << 32) | (unsigned)jA;
        outPack[o0 + row1] = ((u64)__float_as_uint(dB) << 32) | (unsigned)jB;
    } else {
        outVal[o0 + row0] = __float_as_uint(fminf(db0, db1));
        outVal[o0 + row1] = __float_as_uint(fminf(dc0, dc1));
    }
}

// All four passes, one dispatch, 1088 uniform blocks (512 rows x 512 j each;
// all co-resident, uniform length -> no drain tail).
//  [0,   512) fine-cols  : P=tgt,    Q=finep   (16 ch x 16 yb x 2 b)
//  [512, 1024) fine-rows : P=fine,   Q=tgtp,   ARGMIN
//  [1024,1056) coarse-rows: P=coarse, Q=tgtp   (16 ch x 2 b)
//  [1056,1088) coarse-cols: P=tgt,    Q=coarsep (16 yb x 2 b)
__global__ __launch_bounds__(TPB, 8) void pairmin_all(
    const float* __restrict__ coarse, const float* __restrict__ fine,
    const float* __restrict__ tgt,
    const v2f* __restrict__ finep, const v2f* __restrict__ tgtp,
    const v2f* __restrict__ coarsep,
    u64* __restrict__ pfr, unsigned* __restrict__ pfc,
    unsigned* __restrict__ pcr, unsigned* __restrict__ pcc)
{
    const int bx = blockIdx.x;
    if (bx < 512) {
        int chunk = bx & 15, yb = (bx >> 4) & 15, b = bx >> 8;
        pairmin_body<false>(tgt, finep, MT, NF/2, b, yb*512, chunk*256, 256,
                            chunk, B_*MT, nullptr, pfc);
    } else if (bx < 1024) {
        int i = bx - 512;
        int chunk = i & 15, yb = (i >> 4) & 15, b = i >> 8;
        pairmin_body<true>(fine, tgtp, NF, MT/2, b, yb*512, chunk*256, 256,
                           chunk, B_*NF, pfr, nullptr);
    } else if (bx < 1056) {
        int i = bx - 1024;
        int chunk = i & 15, b = i >> 4;
        pairmin_body<false>(coarse, tgtp, NC, MT/2, b, 0, chunk*256, 256,
                            chunk, B_*NC, nullptr, pcr);
    } else {
        int i = bx - 1056;
        int yb = i & 15, b = i >> 4;
        pairmin_body<false>(tgt, coarsep, MT, NC/2, b, yb*512, 0, 256,
                            0, B_*MT, nullptr, pcc);
    }
}

// ---------------------------------------------------------------------------
// tail_all: reduce partials, gather, stats, wedge volumes, final combine.
// Last-arriving block (device-scope counter) does the final combine.
// ---------------------------------------------------------------------------
__global__ __launch_bounds__(TPB) void tail_all(
    const float* __restrict__ fine, const float* __restrict__ tgt,
    const u64* __restrict__ pfr, const unsigned* __restrict__ pfc,
    const unsigned* __restrict__ pcr, const unsigned* __restrict__ pcc,
    double* __restrict__ bs, unsigned* __restrict__ counter,
    float* __restrict__ out)
{
    __shared__ float sp[TPB + 2][3], yp[TPB + 2][3];
    __shared__ double redw[4][9];
    __shared__ double lred[4][13];
    __shared__ int lastflag;
    const int bx = blockIdx.x, tid = threadIdx.x;
    const int wave = tid >> 6, lane = tid & 63;

    double v_s = 0, v_d2f = 0, v_d1c = 0, v_d2c = 0, v_yd2 = 0, v_zs = 0, v_zt = 0;
    double vs = 0, vt = 0;
    int role_b = 0;

    if (bx < 64) {                              // ---- fine-rows ----
        const int base = bx * TPB;
        const int g = base + tid;
        const int b = base >> 13;  role_b = b;
        u64 best = pfr[g];
        #pragma unroll
        for (int c = 1; c < CF; ++c) {
            u64 p = pfr[(size_t)c * (B_ * NF) + g];
            best = p < best ? p : best;
        }
        float d1 = __uint_as_float((unsigned)(best >> 32));
        int idx  = (int)(best & 0xffffffffULL);
        float s = sqrtf(fmaxf(d1, 1e-12f));
        const float* y  = tgt  + ((size_t)b * MT + idx) * 3;
        const float* sr = fine + (size_t)g * 3;
        float y0 = y[0],  y1 = y[1],  y2 = y[2];
        float s0 = sr[0], s1 = sr[1], s2 = sr[2];
        yp[tid][0] = y0; yp[tid][1] = y1; yp[tid][2] = y2;
        sp[tid][0] = s0; sp[tid][1] = s1; sp[tid][2] = s2;
        const int base_b = base & (NF - 1);
        if (tid < 2 && base_b + TPB + tid < NF) {        // halo rows
            int g2 = base + TPB + tid;
            u64 b2 = pfr[g2];
            #pragma unroll
            for (int c = 1; c < CF; ++c) {
                u64 p = pfr[(size_t)c * (B_ * NF) + g2];
                b2 = p < b2 ? p : b2;
            }
            int i2 = (int)(b2 & 0xffffffffULL);
            const float* yh = tgt  + ((size_t)b * MT + i2) * 3;
            const float* sh = fine + (size_t)g2 * 3;
            #pragma unroll
            for (int k = 0; k < 3; ++k) { yp[TPB + tid][k] = yh[k]; sp[TPB + tid][k] = sh[k]; }
        }
        __syncthreads();
        v_s = s;
        float yd = s1 - y1;
        v_yd2 = (double)(yd * yd);
        v_zs  = (double)(s2 * s2);
        v_zt  = (double)(y2 * y2);
        int rb = base_b + tid;
        if (rb <= NF - 3) {          // same f32 exprs as the verified R3 kernel
            {
                const float* a = sp[tid]; const float* c = sp[tid+1]; const float* e = sp[tid+2];
                float c0 = a[1]*c[2] - a[2]*c[1];
                float c1 = a[2]*c[0] - a[0]*c[2];
                float c2 = a[0]*c[1] - a[1]*c[0];
                vs = (double)(c0*e[0] + c1*e[1] + c2*e[2]);
            }
            {
                const float* a = yp[tid]; const float* c = yp[tid+1]; const float* e = yp[tid+2];
                float c0 = a[1]*c[2] - a[2]*c[1];
                float c1 = a[2]*c[0] - a[0]*c[2];
                float c2 = a[0]*c[1] - a[1]*c[0];
                vt = (double)(c0*e[0] + c1*e[1] + c2*e[2]);
            }
        }
    } else if (bx < 128) {                      // ---- fine-cols ----
        const int g = (bx - 64) * TPB + tid;
        unsigned best = pfc[g];
        #pragma unroll
        for (int c = 1; c < CF; ++c) best = min(best, pfc[(size_t)c * (B_ * MT) + g]);
        v_d2f = (double)sqrtf(fmaxf(__uint_as_float(best), 1e-12f));
    } else if (bx < 132) {                      // ---- coarse-rows ----
        const int g = (bx - 128) * TPB + tid;
        unsigned best = pcr[g];
        #pragma unroll
        for (int c = 1; c < 16; ++c) best = min(best, pcr[(size_t)c * (B_ * NC) + g]);
        v_d1c = (double)sqrtf(fmaxf(__uint_as_float(best), 1e-12f));
    } else {                                    // ---- coarse-cols ----
        const int g = (bx - 132) * TPB + tid;
        v_d2c = (double)sqrtf(fmaxf(__uint_as_float(pcc[g]), 1e-12f));
    }

    // block reduce 9 values
    double r9[9] = {v_s, v_d2f, v_d1c, v_d2c, v_yd2, v_zs, v_zt, vs, vt};
    for (int o = 32; o; o >>= 1) {
        #pragma unroll
        for (int k = 0; k < 9; ++k) r9[k] += __shfl_down(r9[k], o);
    }
    if (lane == 0) {
        #pragma unroll
        for (int k = 0; k < 9; ++k) redw[wave][k] = r9[k];
    }
    __syncthreads();
    if (tid == 0) {
        double t9[9];
        #pragma unroll
        for (int k = 0; k < 9; ++k)
            t9[k] = redw[0][k] + redw[1][k] + redw[2][k] + redw[3][k];
        double* o = bs + (size_t)bx * 16;
        #pragma unroll
        for (int k = 0; k < 16; ++k) o[k] = 0.0;
        o[0] = t9[0]; o[1] = t9[1]; o[2] = t9[2]; o[3] = t9[3]; o[4] = t9[4];
        o[5 + role_b]  = t9[5];   // zs
        o[7 + role_b]  = t9[6];   // zt
        o[9 + role_b]  = t9[7];   // vs
        o[11 + role_b] = t9[8];   // vt
        __threadfence();
        unsigned old = atomicAdd(counter, 1u);
        lastflag = (old == TAIL_BLOCKS - 1);
    }
    __syncthreads();
    if (!lastflag) return;

    // ---- final combine (last block only) ----
    __threadfence();
    double c13[13];
    if (tid < TAIL_BLOCKS) {
        const double* p = bs + (size_t)tid * 16;
        #pragma unroll
        for (int k = 0; k < 13; ++k) c13[k] = p[k];
    } else {
        #pragma unroll
        for (int k = 0; k < 13; ++k) c13[k] = 0.0;
    }
    for (int o = 32; o; o >>= 1) {
        #pragma unroll
        for (int k = 0; k < 13; ++k) c13[k] += __shfl_down(c13[k], o);
    }
    if (lane == 0) {
        #pragma unroll
        for (int k = 0; k < 13; ++k) lred[wave][k] = c13[k];
    }
    __syncthreads();
    if (tid == 0) {
        double S[13];
        #pragma unroll
        for (int k = 0; k < 13; ++k)
            S[k] = lred[0][k] + lred[1][k] + lred[2][k] + lred[3][k];
        double m_d1f = S[0] / (double)(B_ * NF);
        double m_d2f = S[1] / (double)(B_ * MT);
        double m_d1c = S[2] / (double)(B_ * NC);
        double m_d2c = S[3] / (double)(B_ * MT);
        double loss_align_fine   = 0.5 * (m_d1f + m_d2f);
        double loss_align_coarse = 0.5 * (m_d1c + m_d2c);
        double loss_ref = S[4] / (double)(B_ * NF);
        double loss_rot = 0.0, loss_geo = 0.0;
        for (int b = 0; b < B_; ++b) {
            double dn = sqrt(S[5 + b]) - sqrt(S[7 + b]);
            loss_rot += dn * dn;
            double dv = (S[9 + b] - S[11 + b]) / 6.0;
            loss_geo += dv * dv;
        }
        loss_rot /= (double)B_;
        loss_geo /= (double)B_;
        out[0] = (float)(loss_rot + loss_ref + loss_align_coarse + loss_align_fine + loss_geo);
    }
}

extern "C" void kernel_launch(void* const* d_in, const int* in_sizes, int n_in,
                              void* d_out, int out_size, void* d_ws, size_t ws_size,
                              hipStream_t stream)
{
    const float* src_coarse = (const float*)d_in[0];
    const float* src_fine   = (const float*)d_in[1];
    const float* tgt        = (const float*)d_in[2];
    float* out = (float*)d_out;
    char*  ws  = (char*)d_ws;

    // ws layout (bytes), identical to R6 (proven to fit). Prefetch may overrun
    // each Qp array by up to 64 B; the following region absorbs it.
    //   [0,        2097152)  u64 pfr[16][16384]   fine-rows (d,j) partials
    //   [2097152,  3145728)  u32 pfc[16][16384]   fine-cols value partials
    //   [3145728,  3211264)  u32 pcr[16][1024]    coarse-rows value partials
    //   [3211264,  3276800)  u32 pcc[1][16384]    coarse-cols value partials
    //   [3276800,  3538944)  float finep[8192*8]  pair-interleaved
    //   [3538944,  3801088)  float tgtp[8192*8]
    //   [3801088,  3817472)  float coarsep[512*8]
    //   [3817472,  3842560)  double bs[196][16]   per-tail-block sums
    //   [3842560,  3842564)  u32 counter          (zeroed by prep)
    u64*      pfr     = (u64*)(ws);
    unsigned* pfc     = (unsigned*)(ws + 2097152);
    unsigned* pcr     = (unsigned*)(ws + 3145728);
    unsigned* pcc     = (unsigned*)(ws + 3211264);
    float*    finep   = (float*)(ws + 3276800);
    float*    tgtp    = (float*)(ws + 3538944);
    float*    coarsep = (float*)(ws + 3801088);
    double*   bs      = (double*)(ws + 3817472);
    unsigned* counter = (unsigned*)(ws + 3842560);

    prep<<<dim3(32), TPB, 0, stream>>>(src_coarse, src_fine, tgt,
                                       finep, tgtp, coarsep, counter);
    pairmin_all<<<dim3(1088), TPB, 0, stream>>>(
        src_coarse, src_fine, tgt,
        (const v2f*)finep, (const v2f*)tgtp, (const v2f*)coarsep,
        pfr, pfc, pcr, pcc);
    tail_all<<<dim3(TAIL_BLOCKS), TPB, 0, stream>>>(
        src_fine, tgt, pfr, pfc, pcr, pcc, bs, counter, out);
}